// Round 1
// baseline (1805.054 us; speedup 1.0000x reference)
//
#include <hip/hip_runtime.h>

// Problem constants (fixed by reference: x is (2, 4, 128, 128, 128) fp32)
#define NBATCH 2
#define NDIM   128
#define NP     (128 * 128 * 128)        // particles per batch = mesh cells
#define DIS_NORM 3.072f                  // 6 * 512 / 1000

// ---------------------------------------------------------------------------
// Kernel 1: per-(batch,channel) sums of the 3 displacement channels.
// ws[plane] accumulates sum over 2M elements; plane = n*3 + c, n in [0,2), c in [0,3).
// ---------------------------------------------------------------------------
__global__ __launch_bounds__(256) void sum_disp_kernel(const float* __restrict__ x,
                                                       float* __restrict__ ws) {
    const int plane = blockIdx.y;            // 0..5
    const int n = plane / 3, c = plane % 3;
    const float4* xp = (const float4*)(x + ((size_t)n * 4 + c) * NP);
    const int nvec = NP / 4;                 // 524288 float4s

    float s = 0.0f;
    for (int i = blockIdx.x * blockDim.x + threadIdx.x; i < nvec;
         i += gridDim.x * blockDim.x) {
        float4 v = xp[i];
        s += (v.x + v.y) + (v.z + v.w);
    }
    // wave64 butterfly reduce
    #pragma unroll
    for (int off = 32; off > 0; off >>= 1) s += __shfl_down(s, off, 64);
    if ((threadIdx.x & 63) == 0) atomicAdd(&ws[plane], s);
}

// ---------------------------------------------------------------------------
// Kernel 2: CIC scatter. One thread per particle; 8 trilinear atomic deposits.
// ---------------------------------------------------------------------------
__global__ __launch_bounds__(256) void scatter_kernel(const float* __restrict__ x,
                                                      const float* __restrict__ ws,
                                                      float* __restrict__ out) {
    const int p = blockIdx.x * 256 + threadIdx.x;   // 0..NP-1 (grid exact)
    const int n = blockIdx.y;

    const float inv_np = 1.0f / (float)NP;
    const float m0 = ws[n * 3 + 0] * inv_np;
    const float m1 = ws[n * 3 + 1] * inv_np;
    const float m2 = ws[n * 3 + 2] * inv_np;

    const size_t base = (size_t)n * 4 * NP;
    const float d0 = x[base + 0 * (size_t)NP + p];
    const float d1 = x[base + 1 * (size_t)NP + p];
    const float d2 = x[base + 2 * (size_t)NP + p];
    const float v  = x[base + 3 * (size_t)NP + p];

    // decode p -> (d, h, w), w fastest
    const int w = p & 127;
    const int h = (p >> 7) & 127;
    const int d = p >> 14;

    const float pd = (d0 - m0) * DIS_NORM + ((float)d + 0.5f);
    const float ph = (d1 - m1) * DIS_NORM + ((float)h + 0.5f);
    const float pw = (d2 - m2) * DIS_NORM + ((float)w + 0.5f);

    const float fd = floorf(pd), fh = floorf(ph), fw = floorf(pw);
    const int id = (int)fd, ih = (int)fh, iw = (int)fw;
    const float rd = pd - fd, rh = ph - fh, rw = pw - fw;

    const float wd[2] = {1.0f - rd, rd};
    const float wh[2] = {1.0f - rh, rh};
    const float wwt[2] = {1.0f - rw, rw};

    float* o = out + (size_t)n * NP;

    #pragma unroll
    for (int dd = 0; dd < 2; ++dd) {
        const int td = id + dd;
        if ((unsigned)td >= (unsigned)NDIM) continue;
        #pragma unroll
        for (int hh = 0; hh < 2; ++hh) {
            const int th = ih + hh;
            if ((unsigned)th >= (unsigned)NDIM) continue;
            const float wdh = v * wd[dd] * wh[hh];
            const int rowbase = (td * NDIM + th) * NDIM;
            #pragma unroll
            for (int wi = 0; wi < 2; ++wi) {
                const int tw = iw + wi;
                if ((unsigned)tw >= (unsigned)NDIM) continue;
                atomicAdd(o + rowbase + tw, wdh * wwt[wi]);
            }
        }
    }
}

extern "C" void kernel_launch(void* const* d_in, const int* in_sizes, int n_in,
                              void* d_out, int out_size, void* d_ws, size_t ws_size,
                              hipStream_t stream) {
    const float* x = (const float*)d_in[0];
    float* out = (float*)d_out;
    float* ws = (float*)d_ws;   // 6 floats: per-(n,c) displacement sums

    // Zero the accumulators (harness poisons them with 0xAA before every call)
    hipMemsetAsync(ws, 0, 6 * sizeof(float), stream);
    hipMemsetAsync(out, 0, (size_t)out_size * sizeof(float), stream);

    // Per-(batch,channel) sums: 6 planes, 128 blocks each
    dim3 sgrid(128, 6);
    sum_disp_kernel<<<sgrid, 256, 0, stream>>>(x, ws);

    // CIC scatter: one thread per particle
    dim3 grid(NP / 256, NBATCH);
    scatter_kernel<<<grid, 256, 0, stream>>>(x, ws, out);
}